// Round 3
// baseline (517.140 us; speedup 1.0000x reference)
//
#include <hip/hip_runtime.h>

// Round 5: 8-wave phase-split schedule (T3+T4 port of the 256^2 8-phase
// template). 512 threads, waves 4Mx2N, BM=256 BN=64 BK=32, LDS dbuf 2x52KB
// (1 block/CU). Per K-tile: 3 phases {ds_reads; s_barrier; lgkmcnt(0);
// setprio(1); MFMA cluster; setprio(0); s_barrier}, stage(t+2) after the
// consumption barrier, counted per-wave vmcnt (7 or 6), never drained in the
// main loop. XCD swizzle REVERTED (R4: doubled FETCH 348->629MB - activation
// reuse wants the default x-fastest order). Slot XOR swizzle kept (conflicts=0).
// convert_bf16: 2 independent vec8 per thread.

#define BM 256
#define BN 64
#define BK 32
#define TILE_BYTES 53248   // 16K input + 16K hidden + 20K weights

typedef __attribute__((ext_vector_type(8))) short          bf16x8;
typedef __attribute__((ext_vector_type(8))) unsigned short u16x8;
typedef __attribute__((ext_vector_type(4))) float          f32x4;

__device__ __forceinline__ unsigned short f2bf(float f) {
    union { float f; unsigned u; } v; v.f = f;
    unsigned r = v.u + 0x7FFFu + ((v.u >> 16) & 1u);  // RNE
    return (unsigned short)(r >> 16);
}

// ---- Pass 1: fp32 -> bf16 conversion into ws ----
// ws layout (elements): [0) input 16777216 | [16777216) hidden 16777216 |
//                       [33554432 + g*1048576) W_g for g=0..4
// Total vec8 = 4,849,664 = 2 * 9472 blocks * 256.
__device__ __forceinline__ void cvt_unit(
    long long u,
    const float* __restrict__ in0, const float* __restrict__ in1,
    const float* __restrict__ w0, const float* __restrict__ w1,
    const float* __restrict__ w2, const float* __restrict__ w3,
    const float* __restrict__ w4, unsigned short* __restrict__ ws)
{
    const long long e = u * 8;
    const float* src;
    if (e < 16777216LL) {
        src = in0 + e;
    } else if (e < 33554432LL) {
        src = in1 + (e - 16777216LL);
    } else {
        const long long t = e - 33554432LL;
        const int g = (int)(t >> 20);
        const long long within = t & 1048575LL;
        const float* w = (g == 0) ? w0 : (g == 1) ? w1 : (g == 2) ? w2 : (g == 3) ? w3 : w4;
        src = w + within;
    }
    const float4 a = *reinterpret_cast<const float4*>(src);
    const float4 b = *reinterpret_cast<const float4*>(src + 4);
    u16x8 o;
    o[0] = f2bf(a.x); o[1] = f2bf(a.y); o[2] = f2bf(a.z); o[3] = f2bf(a.w);
    o[4] = f2bf(b.x); o[5] = f2bf(b.y); o[6] = f2bf(b.z); o[7] = f2bf(b.w);
    *reinterpret_cast<u16x8*>(ws + e) = o;
}

__global__ __launch_bounds__(256) void convert_bf16(
    const float* __restrict__ in0, const float* __restrict__ in1,
    const float* __restrict__ w0, const float* __restrict__ w1,
    const float* __restrict__ w2, const float* __restrict__ w3,
    const float* __restrict__ w4, unsigned short* __restrict__ ws)
{
    const long long u = (long long)blockIdx.x * 256 + threadIdx.x;
    cvt_unit(u,             in0, in1, w0, w1, w2, w3, w4, ws);
    cvt_unit(u + 2424832LL, in0, in1, w0, w1, w2, w3, w4, ws);
}

// ---- async 16B global->LDS ----
__device__ __forceinline__ void async16(const void* g, void* l) {
    __builtin_amdgcn_global_load_lds(
        (const __attribute__((address_space(1))) unsigned int*)g,
        (__attribute__((address_space(3))) unsigned int*)l, 16, 0, 0);
}

#define CFENCE() asm volatile("" ::: "memory")
#define MFMA16(a, b, c) __builtin_amdgcn_mfma_f32_16x16x32_bf16((a), (b), (c), 0, 0, 0)

// ---- Pass 2: fused GRU ----
// Per-tile LDS image (bf16, linear dest as global_load_lds requires):
//   [0, 16384)      sIn  [256 rows][64 B]   (4 x 16B slots per row)
//   [16384, 32768)  sHid [256 rows][64 B]
//   [32768, 53248)  sW[5][64 rows][64 B]
// Slot swizzle: logical 16B slot c of row r stored at physical c ^ ((r>>1)&3)
// (applied to the GLOBAL source at staging; same involution on reads).
// 3328 16B slots = 512 threads * 6.5 -> waves 0-3 stage 7, waves 4-7 stage 6.
__global__ __launch_bounds__(512, 2) void gru_fused(
    const unsigned short* __restrict__ bf,   // ws: bf16 image
    const float* __restrict__ hidden,        // fp32, for epilogue z*h
    const float* __restrict__ b_ri, const float* __restrict__ b_rh,
    const float* __restrict__ b_zi, const float* __restrict__ b_ni,
    const float* __restrict__ b_nh,
    float* __restrict__ out)
{
    const int H = 1024, K = 1024;
    const int BH = 16384 * 1024;

    __shared__ __align__(16) unsigned char sBuf[2][TILE_BYTES];

    const int tid  = threadIdx.x;
    const int wave = tid >> 6;
    const int lane = tid & 63;
    const int quad = lane >> 4;
    const int l16  = lane & 15;
    const int sq   = quad ^ ((l16 >> 1) & 3);   // swizzled 16B slot for reads
    const int wm   = wave >> 1;                 // 0..3 (M position)
    const int wn   = wave & 1;                  // 0..1 (N position)

    const int row0 = blockIdx.y * BM;
    const int col0 = blockIdx.x * BN;

    // Stage source offsets (elements into bf) at k=0. Slot s = j*512 + tid.
    unsigned srcoff[7];
    #pragma unroll
    for (int j = 0; j < 7; ++j) {
        if (j < 6 || tid < 256) {
            const int s = j * 512 + tid;
            if (s < 1024) {                        // input tile: 4 slots/row
                const int r = s >> 2;
                const int c = (s & 3) ^ ((r >> 1) & 3);
                srcoff[j] = (unsigned)((row0 + r) * K + c * 8);
            } else if (s < 2048) {                 // hidden tile
                const int r = (s - 1024) >> 2;
                const int c = ((s - 1024) & 3) ^ ((r >> 1) & 3);
                srcoff[j] = (unsigned)(16777216 + (row0 + r) * K + c * 8);
            } else {                               // weight tiles
                const int t = s - 2048;
                const int g = t >> 8;
                const int tt = t & 255;
                const int n = tt >> 2;
                const int c = (tt & 3) ^ ((n >> 1) & 3);
                srcoff[j] = (unsigned)(33554432u + g * 1048576u + (col0 + n) * K + c * 8);
            }
        }
    }

    auto stage = [&](int kofs, unsigned char* dst) {
        #pragma unroll
        for (int j = 0; j < 7; ++j)
            if (j < 6 || tid < 256)
                async16(bf + srcoff[j] + kofs, dst + j * 8192 + tid * 16);
    };

    // per-wave counted vmcnt: waves 0-3 have 7 loads in flight per tile, 4-7 have 6
    #define WAIT_N() do { if (tid < 256) asm volatile("s_waitcnt vmcnt(7)" ::: "memory"); \
                          else           asm volatile("s_waitcnt vmcnt(6)" ::: "memory"); } while (0)

    f32x4 acc[5][4][2];
    #pragma unroll
    for (int g = 0; g < 5; ++g)
        #pragma unroll
        for (int mi = 0; mi < 4; ++mi)
            #pragma unroll
            for (int ni = 0; ni < 2; ++ni)
                acc[g][mi][ni] = (f32x4){0.f, 0.f, 0.f, 0.f};

    unsigned char* B0 = &sBuf[0][0];
    unsigned char* B1 = &sBuf[1][0];

    // tile body. mode: 0 = stage(t+2)+counted wait, 1 = drain wait only (t=30),
    // 2 = nothing (t=31).
    auto tile = [&](const unsigned char* sb, int stage_k, unsigned char* stage_dst, int mode) {
        // ---------- phase 0: A frags + B(g=0) ; MFMA g=0 (8) ----------
        bf16x8 aIn[4], aHid[4], bb0[2];
        #pragma unroll
        for (int mi = 0; mi < 4; ++mi) {
            const int r = wm * 64 + mi * 16 + l16;
            aIn [mi] = *reinterpret_cast<const bf16x8*>(sb + r * 64 + sq * 16);
            aHid[mi] = *reinterpret_cast<const bf16x8*>(sb + 16384 + r * 64 + sq * 16);
        }
        #pragma unroll
        for (int ni = 0; ni < 2; ++ni) {
            const int n = wn * 32 + ni * 16 + l16;
            bb0[ni] = *reinterpret_cast<const bf16x8*>(sb + 32768 + n * 64 + sq * 16);
        }
        CFENCE(); __builtin_amdgcn_s_barrier(); CFENCE();
        asm volatile("s_waitcnt lgkmcnt(0)" ::: "memory");
        __builtin_amdgcn_s_setprio(1);
        #pragma unroll
        for (int ni = 0; ni < 2; ++ni)
            #pragma unroll
            for (int mi = 0; mi < 4; ++mi)
                acc[0][mi][ni] = MFMA16(aIn[mi], bb0[ni], acc[0][mi][ni]);
        __builtin_amdgcn_s_setprio(0);
        CFENCE(); __builtin_amdgcn_s_barrier(); CFENCE();

        // ---------- phase 1: B(g=1,2) ; MFMA g=1 (aHid), g=2 (aIn) (16) ----------
        bf16x8 bb1[2], bb2[2];
        #pragma unroll
        for (int ni = 0; ni < 2; ++ni) {
            const int n = wn * 32 + ni * 16 + l16;
            bb1[ni] = *reinterpret_cast<const bf16x8*>(sb + 32768 + 4096 + n * 64 + sq * 16);
            bb2[ni] = *reinterpret_cast<const bf16x8*>(sb + 32768 + 8192 + n * 64 + sq * 16);
        }
        CFENCE(); __builtin_amdgcn_s_barrier(); CFENCE();
        asm volatile("s_waitcnt lgkmcnt(0)" ::: "memory");
        __builtin_amdgcn_s_setprio(1);
        #pragma unroll
        for (int ni = 0; ni < 2; ++ni)
            #pragma unroll
            for (int mi = 0; mi < 4; ++mi)
                acc[1][mi][ni] = MFMA16(aHid[mi], bb1[ni], acc[1][mi][ni]);
        #pragma unroll
        for (int ni = 0; ni < 2; ++ni)
            #pragma unroll
            for (int mi = 0; mi < 4; ++mi)
                acc[2][mi][ni] = MFMA16(aIn[mi], bb2[ni], acc[2][mi][ni]);
        __builtin_amdgcn_s_setprio(0);
        CFENCE(); __builtin_amdgcn_s_barrier(); CFENCE();

        // ---------- phase 2: B(g=3,4) ; MFMA g=3 (aIn), g=4 (aHid) (16) ----------
        bf16x8 bb3[2], bb4[2];
        #pragma unroll
        for (int ni = 0; ni < 2; ++ni) {
            const int n = wn * 32 + ni * 16 + l16;
            bb3[ni] = *reinterpret_cast<const bf16x8*>(sb + 32768 + 12288 + n * 64 + sq * 16);
            bb4[ni] = *reinterpret_cast<const bf16x8*>(sb + 32768 + 16384 + n * 64 + sq * 16);
        }
        CFENCE(); __builtin_amdgcn_s_barrier(); CFENCE();
        asm volatile("s_waitcnt lgkmcnt(0)" ::: "memory");
        __builtin_amdgcn_s_setprio(1);
        #pragma unroll
        for (int ni = 0; ni < 2; ++ni)
            #pragma unroll
            for (int mi = 0; mi < 4; ++mi)
                acc[3][mi][ni] = MFMA16(aIn[mi], bb3[ni], acc[3][mi][ni]);
        #pragma unroll
        for (int ni = 0; ni < 2; ++ni)
            #pragma unroll
            for (int mi = 0; mi < 4; ++mi)
                acc[4][mi][ni] = MFMA16(aHid[mi], bb4[ni], acc[4][mi][ni]);
        __builtin_amdgcn_s_setprio(0);
        CFENCE(); __builtin_amdgcn_s_barrier(); CFENCE();
        // all waves' ds_reads of sb are complete (each passed lgkmcnt(0) before
        // its phase-2 MFMAs, then the barrier) -> safe to restage this buffer.

        if (mode == 0) {
            stage(stage_k, stage_dst);           // tile t+2 into the buffer just consumed
            WAIT_N();                            // tile t+1's loads complete; t+2's stay in flight
            CFENCE(); __builtin_amdgcn_s_barrier(); CFENCE();
        } else if (mode == 1) {
            asm volatile("s_waitcnt vmcnt(0)" ::: "memory");  // drain: last tile's loads
            CFENCE(); __builtin_amdgcn_s_barrier(); CFENCE();
        }
    };

    // ---- pipelined K loop: 32 tiles, depth-1 prefetch, counted vmcnt ----
    stage(0,  B0);
    stage(BK, B1);
    WAIT_N();                                    // tile 0 ready (tile 1 in flight)
    CFENCE(); __builtin_amdgcn_s_barrier(); CFENCE();

    #pragma unroll 1
    for (int i = 0; i < 15; ++i) {
        tile(B0, (2 * i + 2) * BK, B0, 0);
        tile(B1, (2 * i + 3) * BK, B1, 0);
    }
    tile(B0, 0, nullptr, 1);                     // t=30: drain tile 31's loads
    tile(B1, 0, nullptr, 2);                     // t=31

    // Epilogue: C/D layout row = quad*4 + r4, col = l16 per 16x16 tile.
    #pragma unroll
    for (int ni = 0; ni < 2; ++ni) {
        const int gcol = col0 + wn * 32 + ni * 16 + l16;
        const float bri = b_ri[gcol], brh = b_rh[gcol], bzi = b_zi[gcol];
        const float bni = b_ni[gcol], bnh = b_nh[gcol];
        #pragma unroll
        for (int mi = 0; mi < 4; ++mi) {
            #pragma unroll
            for (int r4 = 0; r4 < 4; ++r4) {
                const int grow = row0 + wm * 64 + mi * 16 + quad * 4 + r4;
                const float g_ri = acc[0][mi][ni][r4];
                const float g_rh = acc[1][mi][ni][r4];
                const float g_zi = acc[2][mi][ni][r4];
                const float g_ni = acc[3][mi][ni][r4];
                const float g_nh = acc[4][mi][ni][r4];
                const float rh = g_rh + brh;                  // shared by r and z (reference bug kept)
                const float rr = 1.f / (1.f + __expf(-(g_ri + bri + rh)));
                const float zz = 1.f / (1.f + __expf(-(g_zi + bzi + rh)));
                const float nn = tanhf(g_ni + bni + rr * (g_nh + bnh));
                const float h  = hidden[(long long)grow * H + gcol];
                const float o  = (1.f - zz) * nn + zz * h;
                out[(long long)grow * H + gcol]      = o;
                out[BH + (long long)grow * H + gcol] = o;
            }
        }
    }
}

extern "C" void kernel_launch(void* const* d_in, const int* in_sizes, int n_in,
                              void* d_out, int out_size, void* d_ws, size_t ws_size,
                              hipStream_t stream) {
    const float* input  = (const float*)d_in[0];
    const float* hidden = (const float*)d_in[1];
    const float* W_ri = (const float*)d_in[2];
    const float* b_ri = (const float*)d_in[3];
    const float* W_rh = (const float*)d_in[4];
    const float* b_rh = (const float*)d_in[5];
    const float* W_zi = (const float*)d_in[6];
    const float* b_zi = (const float*)d_in[7];
    // d_in[8], d_in[9] = W_z_h, b_z_h: dead per the reference's bug (z uses r_h)
    const float* W_ni = (const float*)d_in[10];
    const float* b_ni = (const float*)d_in[11];
    const float* W_nh = (const float*)d_in[12];
    const float* b_nh = (const float*)d_in[13];
    float* out = (float*)d_out;
    unsigned short* ws = (unsigned short*)d_ws;

    // gate order in ws: 0=r_i 1=r_h 2=z_i 3=n_i 4=n_h
    convert_bf16<<<9472, 256, 0, stream>>>(input, hidden, W_ri, W_rh, W_zi, W_ni, W_nh, ws);

    dim3 grid(1024 / BN, 16384 / BM);  // (16, 64)
    gru_fused<<<grid, 512, 0, stream>>>(ws, hidden, b_ri, b_rh, b_zi, b_ni, b_nh, out);
}